// Round 9
// baseline (360.157 us; speedup 1.0000x reference)
//
#include <hip/hip_runtime.h>
#include <math.h>

typedef unsigned short u16;
typedef __attribute__((ext_vector_type(4))) short short4v;
typedef __attribute__((ext_vector_type(8))) short short8;
typedef __attribute__((ext_vector_type(8))) __bf16 bf16x8;
typedef __attribute__((ext_vector_type(4))) float f32x4;
typedef __attribute__((ext_vector_type(16))) float f32x16;
typedef __attribute__((ext_vector_type(4))) int i32x4;

#define SLEN  2048
#define DM    3584
#define NQKVC 4608
#define HDIM  128
#define NHEAD 28
#define NKVH  4
#define GRP   7
// 1/sqrt(128) * log2(e): Q pre-scaled so attention works in base-2 exp
#define QSCALE 0.12751744f

#if __has_builtin(__builtin_amdgcn_exp2f)
#define EXP2(x) __builtin_amdgcn_exp2f(x)
#else
#define EXP2(x) exp2f(x)
#endif

__device__ __forceinline__ float b2f(u16 u){ union{unsigned i; float f;} v; v.i = ((unsigned)u)<<16; return v.f; }
__device__ __forceinline__ u16 f2b(float f){ union{float f; unsigned i;} v; v.f = f; unsigned r = v.i + 0x7FFFu + ((v.i>>16)&1u); return (u16)(r>>16); }

__device__ __forceinline__ f32x4 mfma16(short8 a, short8 b, f32x4 c){
  return __builtin_amdgcn_mfma_f32_16x16x32_bf16(__builtin_bit_cast(bf16x8,a), __builtin_bit_cast(bf16x8,b), c, 0, 0, 0);
}
__device__ __forceinline__ f32x16 mfma32(short8 a, short8 b, f32x16 c){
  return __builtin_amdgcn_mfma_f32_32x32x16_bf16(__builtin_bit_cast(bf16x8,a), __builtin_bit_cast(bf16x8,b), c, 0, 0, 0);
}
__device__ __forceinline__ f32x16 zero16(){
  f32x16 z;
  #pragma unroll
  for (int i = 0; i < 16; ++i) z[i] = 0.f;
  return z;
}

__device__ __forceinline__ void gload_lds16(const u16* g, u16* l){
  __builtin_amdgcn_global_load_lds((const __attribute__((address_space(1))) void*)g,
                                   (__attribute__((address_space(3))) void*)l, 16, 0, 0);
}

// ---------------- cast f32 -> bf16 with per-row swizzle (GEMM-A layout) ----------------
// element (r,k) stored at col (k & ~63) | ((k ^ ((r&7)<<3)) & 63)  [8-elem groups]
__global__ void cvt_swz_kernel(const float* __restrict__ src, u16* __restrict__ dst){
  int idx = blockIdx.x * blockDim.x + threadIdx.x;      // one 8-elem group each; grid exact
  int r = idx / (DM / 8), g = idx % (DM / 8);
  const float4* s4 = (const float4*)(src + (size_t)idx * 8);
  float4 a = s4[0], b = s4[1];
  short8 o;
  o[0]=(short)f2b(a.x); o[1]=(short)f2b(a.y); o[2]=(short)f2b(a.z); o[3]=(short)f2b(a.w);
  o[4]=(short)f2b(b.x); o[5]=(short)f2b(b.y); o[6]=(short)f2b(b.z); o[7]=(short)f2b(b.w);
  int gs = (g & ~7) | ((g & 7) ^ (r & 7));
  *(short8*)(dst + (size_t)r * DM + gs * 8) = o;
}

// ---------------- merged transpose+cast for Wq/Wk/Wv/Wo (swizzled B^T panels) ----------
__global__ void transpose_cvt_all_kernel(const float* __restrict__ Wq, const float* __restrict__ Wk,
                                         const float* __restrict__ Wv, const float* __restrict__ Wo,
                                         u16* __restrict__ wqkvT, u16* __restrict__ woT){
  int z = blockIdx.z;
  const float* src; u16* dst; int N;
  if (z == 0){ src = Wq; dst = wqkvT;                          N = DM;  }
  else if (z == 1){ src = Wk; dst = wqkvT + (size_t)DM * DM;   N = 512; }
  else if (z == 2){ src = Wv; dst = wqkvT + (size_t)(DM+512)*DM; N = 512; }
  else { src = Wo; dst = woT; N = DM; }
  int nb = blockIdx.y * 32;
  if (nb >= N) return;
  int kb = blockIdx.x * 64;

  __shared__ u16 lt[32 * 68];
  int t = threadIdx.x, tx = t & 7, ty = t >> 3;   // ty 0..31
  #pragma unroll
  for (int i = 0; i < 2; ++i){
    int k = ty + 32 * i;
    float4 v = *(const float4*)(src + (size_t)(kb + k) * N + nb + tx * 4);
    lt[(tx * 4 + 0) * 68 + k] = f2b(v.x);
    lt[(tx * 4 + 1) * 68 + k] = f2b(v.y);
    lt[(tx * 4 + 2) * 68 + k] = f2b(v.z);
    lt[(tx * 4 + 3) * 68 + k] = f2b(v.w);
  }
  __syncthreads();
  int n = ty, kc = tx;
  short4v lo = *(const short4v*)(lt + n * 68 + kc * 8);
  short4v hi4 = *(const short4v*)(lt + n * 68 + kc * 8 + 4);
  short8 o;
  o[0]=lo[0]; o[1]=lo[1]; o[2]=lo[2]; o[3]=lo[3];
  o[4]=hi4[0]; o[5]=hi4[1]; o[6]=hi4[2]; o[7]=hi4[3];
  int kcs = kc ^ (ty & 7);                          // row-keyed swizzle within 64-col chunk
  *(short8*)(dst + (size_t)(nb + n) * DM + kb + kcs * 8) = o;
}

// ---------------- bias pack: [bq | bk | bv] -> f32[4608] ----------------
__global__ void pack_bias_kernel(const float* bq, const float* bk, const float* bv, float* o){
  int n = blockIdx.x * 256 + threadIdx.x;
  if (n >= NQKVC) return;
  o[n] = (n < DM) ? bq[n] : (n < DM + 512 ? bk[n - DM] : bv[n - DM - 512]);
}

// ---------------- 256x256 8-phase bf16 GEMM (T2+T3+T4+T5) ----------------
// C[M][N] = A[M][K] * B^T[N][K]. A,B stored PRE-SWIZZLED (col ^= (row&7)<<3 within
// 64-col chunks) so linear global_load_lds lands a bank-conflict-free LDS image.
// 512 threads = 8 waves (2M x 4N), per-wave 128x64 out, BK=64, LDS 128 KiB dbuf.
//
// Stage/read ledger (fixed from round 8's races):
//   reads:  buf0 A @ph1,ph3 ; buf0 B @ph1,ph2 ; buf1 A @ph5,ph7 ; buf1 B @ph5,ph6
//   stages: ph1 A1(kt1,buf1) | ph3 B0(kt0+2) | ph4 B1+A0(kt0+2) | ph5 A1(kt0+2)
//           ph7 B0(kt1+2) | ph8 B1+A0(kt1+2)      -- every stage > last read of region
//   vmcnt(6) @ph4 completes {prev ph7, prev ph8, ph1} = tile kt1 before ph5 reads;
//   vmcnt(6) @ph8 completes {ph3,ph4,ph5} = tile kt0+2 before next ph1 reads.
//   Tail: out-of-range stages clamp to kt-2 (same buffer, identical bytes) so the
//   vmcnt ledger stays uniform; a ghost rewrite of identical data is benign.
template<int OUTF32>
__global__ __launch_bounds__(512, 1)
void gemm256_kernel(const u16* __restrict__ A, const u16* __restrict__ B, void* __restrict__ Cout,
                    const float* __restrict__ bias, int K, int lda, int ldb, int ldc){
  __shared__ __align__(16) u16 As[2][16384];
  __shared__ __align__(16) u16 Bs[2][16384];
  int t = threadIdx.x, w = t >> 6, l = t & 63, lm = l & 15, lh = l >> 4;
  int wm = w >> 2, wn = w & 3;
  int m0 = blockIdx.x * 256, n0 = blockIdx.y * 256;
  int nkt = K >> 6;
  int tr = t >> 3, tc = (t & 7) * 8;
  int swz = (lm & 7) << 3;

  const u16* agl = A + (size_t)(m0 + tr) * lda + tc;
  const u16* bgl = B + (size_t)(n0 + tr) * ldb + tc;
  u16* al0 = &As[0][tr * 64 + tc];
  u16* bl0 = &Bs[0][tr * 64 + tc];

  f32x4 acc[8][4];
  #pragma unroll
  for (int i = 0; i < 8; ++i)
    #pragma unroll
    for (int j = 0; j < 4; ++j) acc[i][j] = (f32x4){0.f, 0.f, 0.f, 0.f};

#define STG_A(buf, kt, h) do{ int _kt = ((kt) < nkt) ? (kt) : ((kt) - 2); \
    const u16* _s = agl + (size_t)((h) * 128) * lda + ((size_t)_kt << 6); \
    u16* _d = al0 + (buf) * 16384 + (h) * 8192; \
    gload_lds16(_s, _d); \
    gload_lds16(_s + ((size_t)lda << 6), _d + 4096); }while(0)
#define STG_B(buf, kt, h) do{ int _kt = ((kt) < nkt) ? (kt) : ((kt) - 2); \
    const u16* _s = bgl + (size_t)((h) * 128) * ldb + ((size_t)_kt << 6); \
    u16* _d = bl0 + (buf) * 16384 + (h) * 8192; \
    gload_lds16(_s, _d); \
    gload_lds16(_s + ((size_t)ldb << 6), _d + 4096); }while(0)
#define RD_A(buf, mh) do{ \
    _Pragma("unroll") for (int fm = 0; fm < 4; ++fm) \
    _Pragma("unroll") for (int ks = 0; ks < 2; ++ks) \
      af[fm][ks] = *(const short8*)(&As[buf][(wm*128 + ((mh)*4+fm)*16 + lm)*64 + ((ks*32 + lh*8) ^ swz)]); }while(0)
#define RD_B(dst, buf, nh) do{ \
    _Pragma("unroll") for (int fn = 0; fn < 2; ++fn) \
    _Pragma("unroll") for (int ks = 0; ks < 2; ++ks) \
      dst[fn][ks] = *(const short8*)(&Bs[buf][(wn*64 + ((nh)*2+fn)*16 + lm)*64 + ((ks*32 + lh*8) ^ swz)]); }while(0)
#define QUAD(mh, nh, BF) do{ \
    _Pragma("unroll") for (int fm = 0; fm < 4; ++fm) \
    _Pragma("unroll") for (int fn = 0; fn < 2; ++fn){ \
      acc[(mh)*4+fm][(nh)*2+fn] = mfma16(af[fm][0], BF[fn][0], acc[(mh)*4+fm][(nh)*2+fn]); \
      acc[(mh)*4+fm][(nh)*2+fn] = mfma16(af[fm][1], BF[fn][1], acc[(mh)*4+fm][(nh)*2+fn]); } }while(0)
#define BAR_MID \
    __builtin_amdgcn_s_barrier(); \
    asm volatile("s_waitcnt lgkmcnt(0)" ::: "memory"); \
    __builtin_amdgcn_sched_barrier(0); \
    __builtin_amdgcn_s_setprio(1);
#define BAR_END \
    __builtin_amdgcn_s_setprio(0); \
    __builtin_amdgcn_s_barrier();
#define BAR_END_V \
    __builtin_amdgcn_s_setprio(0); \
    asm volatile("s_waitcnt vmcnt(6)" ::: "memory"); \
    __builtin_amdgcn_sched_barrier(0); \
    __builtin_amdgcn_s_barrier();

  // prologue: tile0 fully (8 loads, oldest), then tile1 B0,B1,A0 (6 in flight)
  STG_A(0, 0, 0); STG_A(0, 0, 1); STG_B(0, 0, 0); STG_B(0, 0, 1);
  STG_B(1, 1, 0); STG_B(1, 1, 1); STG_A(1, 1, 0);
  asm volatile("s_waitcnt vmcnt(6)" ::: "memory");
  __builtin_amdgcn_sched_barrier(0);
  __builtin_amdgcn_s_barrier();

  short8 af[4][2], bf0[2][2], bf1[2][2];
  int niter = nkt >> 1;
  for (int it = 0; it < niter; ++it){
    int kt0 = 2 * it, kt1 = kt0 + 1;
    // ph1: read A0,B0(buf0); stage A1(kt1 -> buf1)
    RD_A(0, 0); RD_B(bf0, 0, 0);
    STG_A(1, kt1, 1);
    BAR_MID; QUAD(0, 0, bf0); BAR_END;
    // ph2: read B1(buf0); no stage
    RD_B(bf1, 0, 1);
    BAR_MID; QUAD(0, 1, bf1); BAR_END;
    // ph3: read A1(buf0) [last buf0 read]; stage B0(kt0+2 -> buf0)
    RD_A(0, 1);
    STG_B(0, kt0 + 2, 0);
    BAR_MID; QUAD(1, 1, bf1); BAR_END;
    // ph4: stage B1+A0(kt0+2 -> buf0); vmcnt(6) -> tile kt1 landed
    STG_B(0, kt0 + 2, 1);
    STG_A(0, kt0 + 2, 0);
    BAR_MID; QUAD(1, 0, bf0); BAR_END_V;
    // ph5: read A0,B0(buf1); stage A1(kt0+2 -> buf0)
    RD_A(1, 0); RD_B(bf0, 1, 0);
    STG_A(0, kt0 + 2, 1);
    BAR_MID; QUAD(0, 0, bf0); BAR_END;
    // ph6: read B1(buf1); no stage
    RD_B(bf1, 1, 1);
    BAR_MID; QUAD(0, 1, bf1); BAR_END;
    // ph7: read A1(buf1) [last buf1 read]; stage B0(kt1+2 -> buf1)
    RD_A(1, 1);
    STG_B(1, kt1 + 2, 0);
    BAR_MID; QUAD(1, 1, bf1); BAR_END;
    // ph8: stage B1+A0(kt1+2 -> buf1); vmcnt(6) -> tile kt0+2 landed
    STG_B(1, kt1 + 2, 1);
    STG_A(1, kt1 + 2, 0);
    BAR_MID; QUAD(1, 0, bf0); BAR_END_V;
  }

  // epilogue
  #pragma unroll
  for (int fm = 0; fm < 8; ++fm){
    #pragma unroll
    for (int fn = 0; fn < 4; ++fn){
      int n = n0 + wn * 64 + fn * 16 + lm;
      float bv = OUTF32 ? 0.f : bias[n];
      #pragma unroll
      for (int j = 0; j < 4; ++j){
        int m = m0 + wm * 128 + fm * 16 + lh * 4 + j;
        float v = acc[fm][fn][j] + bv;
        if (OUTF32) ((float*)Cout)[(size_t)m * ldc + n] = v;
        else        ((u16*)Cout)[(size_t)m * ldc + n]  = f2b(v);
      }
    }
  }
#undef STG_A
#undef STG_B
#undef RD_A
#undef RD_B
#undef QUAD
#undef BAR_MID
#undef BAR_END
#undef BAR_END_V
}

// ---------------- RoPE + head layout ----------------
// Qr[28][S][128] row-major (PRE-SCALED by QSCALE); Kswz[4][32][8192]: per 64x128 tile,
// u16 index r*128 + (d ^ ((r&7)<<3)) (XOR-swizzled LDS image for linear global_load_lds)
__global__ void rope_layout_kernel(const u16* __restrict__ qkv, const float* __restrict__ cosp,
                                   const float* __restrict__ sinp, u16* __restrict__ Qr, u16* __restrict__ Kswz){
  int s = blockIdx.x, y = blockIdx.y, d = threadIdx.x;
  int base = (y < NHEAD) ? y * HDIM : DM + (y - NHEAD) * HDIM;
  const u16* row = qkv + (size_t)s * NQKVC + base;
  float x  = b2f(row[d]);
  float xp = b2f(row[d < 64 ? d + 64 : d - 64]);
  float rot = (d < 64) ? -xp : xp;
  int axis = (d < 32) ? 0 : (d < 80 ? 1 : 2);
  float c  = cosp[axis * (SLEN * HDIM) + s * HDIM + d];
  float sn = sinp[axis * (SLEN * HDIM) + s * HDIM + d];
  float val = x * c + rot * sn;
  if (y < NHEAD){
    Qr[((size_t)y * SLEN + s) * HDIM + d] = f2b(val * QSCALE);
  } else {
    int kh = y - NHEAD, kt = s >> 6, rr = s & 63;
    Kswz[(((size_t)kh * 32 + kt) << 13) + rr * 128 + (d ^ ((rr & 7) << 3))] = f2b(val);
  }
}

// ---------------- V transpose into swizzled tiles ----------------
// Vswz[4][32][8192]: per 128x64 tile (row=d, col=s%64), u16 index d*64 + (c ^ ((d&7)<<3))
__global__ void v_transpose_kernel(const u16* __restrict__ qkv, u16* __restrict__ Vswz){
  __shared__ u16 tile[32][34];
  int kh = blockIdx.z;
  int sb = blockIdx.x * 32, db = blockIdx.y * 32;
  int tx = threadIdx.x, ty = threadIdx.y;
  #pragma unroll
  for (int i = 0; i < 4; ++i){
    int s = sb + ty + i * 8;
    tile[ty + i * 8][tx] = qkv[(size_t)s * NQKVC + DM + 512 + kh * HDIM + db + tx];
  }
  __syncthreads();
  #pragma unroll
  for (int i = 0; i < 4; ++i){
    int d = db + ty + i * 8;
    int s = sb + tx;
    Vswz[(((size_t)kh * 32 + (s >> 6)) << 13) + d * 64 + ((s & 63) ^ ((d & 7) << 3))] = tile[tx][ty + i * 8];
  }
}

// ---------------- causal GQA flash attention (swapped QK^T, 32x32 MFMA) ----------------
#define PV_HALF(PK, KH2) do { \
  unsigned s0 = __shfl_xor(hi ? PK[0] : PK[2], 32, 64); \
  unsigned s1 = __shfl_xor(hi ? PK[1] : PK[3], 32, 64); \
  unsigned s2 = __shfl_xor(hi ? PK[4] : PK[6], 32, 64); \
  unsigned s3 = __shfl_xor(hi ? PK[5] : PK[7], 32, 64); \
  i32x4 fa = { (int)(hi ? s0 : PK[0]), (int)(hi ? s1 : PK[1]), \
               (int)(hi ? PK[2] : s0), (int)(hi ? PK[3] : s1) }; \
  i32x4 fb = { (int)(hi ? s2 : PK[4]), (int)(hi ? s3 : PK[5]), \
               (int)(hi ? PK[6] : s2), (int)(hi ? PK[7] : s3) }; \
  short8 pf0 = __builtin_bit_cast(short8, fa); \
  short8 pf1 = __builtin_bit_cast(short8, fb); \
  _Pragma("unroll") \
  for (int dt = 0; dt < 4; ++dt){ \
    const u16* vrow = vsb + (dt * 32 + lq) * 64; \
    short8 vf0 = *(const short8*)(vrow + (((KH2) * 32 + hi * 8) ^ swz)); \
    short8 vf1 = *(const short8*)(vrow + (((KH2) * 32 + 16 + hi * 8) ^ swz)); \
    oacc[dt] = mfma32(vf0, pf0, oacc[dt]); \
    oacc[dt] = mfma32(vf1, pf1, oacc[dt]); \
  } \
} while(0)

__global__ __launch_bounds__(256, 1)
void attn_kernel(const u16* __restrict__ Qr, const u16* __restrict__ Kswz,
                 const u16* __restrict__ Vswz, u16* __restrict__ O){
  int pairid = blockIdx.x, h = blockIdx.y, kh = h / GRP;
  int t = threadIdx.x, w = t >> 6, l = t & 63;
  int lq = l & 31, hi = l >> 5;
  int swz = (l & 7) << 3;

  __shared__ __align__(16) u16 smem[32768];  // Ks dbuf @0, Vs dbuf @16384; epilogue scratch reuses

  const u16* kg = Kswz + (((size_t)kh * 32) << 13) + t * 8;
  const u16* vg = Vswz + (((size_t)kh * 32) << 13) + t * 8;

  for (int half = 0; half < 2; ++half){
    int qt = half ? (15 - pairid) : pairid;
    int q0 = qt * 128;
    int qrow = q0 + w * 32 + lq;
    int ktstage = 2 * qt + 1;
    int ktw = 2 * qt + (w >> 1);

    __syncthreads();   // protect LDS reuse across passes

    short8 qf[8];
    const u16* qb = Qr + ((size_t)h * SLEN + qrow) * HDIM + hi * 8;
    #pragma unroll
    for (int dc = 0; dc < 8; ++dc) qf[dc] = *(const short8*)(qb + dc * 16);

    f32x16 oacc[4];
    #pragma unroll
    for (int i = 0; i < 4; ++i) oacc[i] = zero16();
    float mrun = -1.0e30f, lsum = 0.f;

    #pragma unroll
    for (int i = 0; i < 4; ++i){
      gload_lds16(kg + i * 2048, smem + t * 8 + i * 2048);
      gload_lds16(vg + i * 2048, smem + 16384 + t * 8 + i * 2048);
    }
    asm volatile("s_waitcnt vmcnt(0)" ::: "memory");
    __syncthreads();

    int buf = 0;
    for (int kt = 0; kt <= ktstage; ++kt){
      if (kt < ktstage){
        const u16* kg2 = kg + ((size_t)(kt + 1) << 13);
        const u16* vg2 = vg + ((size_t)(kt + 1) << 13);
        u16* kdst = smem + ((buf ^ 1) << 13) + t * 8;
        u16* vdst = smem + 16384 + ((buf ^ 1) << 13) + t * 8;
        #pragma unroll
        for (int i = 0; i < 4; ++i){
          gload_lds16(kg2 + i * 2048, kdst + i * 2048);
          gload_lds16(vg2 + i * 2048, vdst + i * 2048);
        }
      }
      if (kt <= ktw){
        const u16* ksb = smem + (buf << 13);
        const u16* vsb = smem + 16384 + (buf << 13);
        f32x16 st0 = zero16(), st1 = zero16();
        #pragma unroll
        for (int dc = 0; dc < 8; ++dc){
          int dofs = (dc * 16 + hi * 8) ^ swz;
          short8 kf0 = *(const short8*)(ksb + lq * 128 + dofs);
          short8 kf1 = *(const short8*)(ksb + (32 + lq) * 128 + dofs);
          st0 = mfma32(kf0, qf[dc], st0);
          st1 = mfma32(kf1, qf[dc], st1);
        }
        if (kt == ktw){
          int kbase = kt * 64 - qrow;
          #pragma unroll
          for (int i = 0; i < 16; ++i){
            int k0 = (i & 3) + 8 * (i >> 2) + 4 * hi;
            if (kbase + k0 > 0)      st0[i] = -3.0e38f;
            if (kbase + 32 + k0 > 0) st1[i] = -3.0e38f;
          }
        }
        float pmax = st0[0];
        #pragma unroll
        for (int i = 1; i < 16; ++i) pmax = fmaxf(pmax, st0[i]);
        #pragma unroll
        for (int i = 0; i < 16; ++i) pmax = fmaxf(pmax, st1[i]);
        if (!__all(pmax - mrun <= 8.f)){
          float mo = fmaxf(pmax, __shfl_xor(pmax, 32, 64));
          float mn = fmaxf(mrun, mo);
          float al = EXP2(mrun - mn);
          mrun = mn;
          lsum *= al;
          #pragma unroll
          for (int i2 = 0; i2 < 4; ++i2)
            #pragma unroll
            for (int i = 0; i < 16; ++i) oacc[i2][i] *= al;
        }
        unsigned pk0[8], pk1[8];
        float ls = 0.f;
        #pragma unroll
        for (int m = 0; m < 8; ++m){
          float a0 = EXP2(st0[2*m] - mrun), b0 = EXP2(st0[2*m+1] - mrun);
          float a1 = EXP2(st1[2*m] - mrun), b1 = EXP2(st1[2*m+1] - mrun);
          ls += (a0 + b0) + (a1 + b1);
          pk0[m] = (unsigned)f2b(a0) | ((unsigned)f2b(b0) << 16);
          pk1[m] = (unsigned)f2b(a1) | ((unsigned)f2b(b1) << 16);
        }
        lsum += ls;
        PV_HALF(pk0, 0);
        PV_HALF(pk1, 1);
      }
      asm volatile("s_waitcnt vmcnt(0)" ::: "memory");
      __syncthreads();
      buf ^= 1;
    }

    float lt = lsum + __shfl_xor(lsum, 32, 64);
    float inv = 1.0f / lt;
    u16* scr = smem + w * 4352;
    #pragma unroll
    for (int dt = 0; dt < 4; ++dt){
      #pragma unroll
      for (int m = 0; m < 8; ++m){
        float a = oacc[dt][2*m] * inv, b = oacc[dt][2*m+1] * inv;
        unsigned pw = (unsigned)f2b(a) | ((unsigned)f2b(b) << 16);
        int d = dt * 32 + 8 * (m >> 1) + 2 * (m & 1) + 4 * hi;
        *(unsigned*)(scr + lq * 136 + d) = pw;
      }
    }
    int r2 = l >> 1, cbase = (l & 1) * 8;
    int srow = q0 + w * 32 + r2;
    u16* orow = O + (size_t)srow * DM + h * HDIM;
    // store with per-row swizzle so Obuf is a valid pre-swizzled GEMM-A panel
    #pragma unroll
    for (int c = 0; c < 8; ++c){
      int gi = (l & 1) + 2 * c;
      int gs = (gi & 8) | ((gi & 7) ^ (srow & 7));
      short8 v8 = *(const short8*)(scr + r2 * 136 + cbase + c * 16);
      *(short8*)(orow + gs * 8) = v8;
    }
  }
}

extern "C" void kernel_launch(void* const* d_in, const int* in_sizes, int n_in,
                              void* d_out, int out_size, void* d_ws, size_t ws_size,
                              hipStream_t stream){
  const float* hidden = (const float*)d_in[0];
  // d_in[1] = attention_mask (causal additive, exploited analytically)
  const float* cosp = (const float*)d_in[2];
  const float* sinp = (const float*)d_in[3];
  const float* Wq = (const float*)d_in[4];
  const float* bq = (const float*)d_in[5];
  const float* Wk = (const float*)d_in[6];
  const float* bk = (const float*)d_in[7];
  const float* Wv = (const float*)d_in[8];
  const float* bv = (const float*)d_in[9];
  const float* Wo = (const float*)d_in[10];
  float* out = (float*)d_out;

  char* wsb = (char*)d_ws;
  u16* hid_b = (u16*)(wsb);                       // [2048][3584] bf16 swz : 14,680,064 B
  u16* wqkvT = (u16*)(wsb + 14680064);            // [4608][3584] bf16 swz : 33,030,144 B
  u16* woT   = (u16*)(wsb + 47710208);            // [3584][3584] bf16 swz : 25,690,112 B
  u16* qkv   = (u16*)(wsb + 73400320);            // [2048][4608] bf16     : 18,874,368 B
  u16* Qr    = (u16*)(wsb + 92274688);            // [28][2048][128]       : 14,680,064 B
  u16* Kswz  = (u16*)(wsb + 106954752);           // [4][32][8192]         :  2,097,152 B
  u16* Vswz  = (u16*)(wsb + 109051904);           // [4][32][8192]         :  2,097,152 B
  u16* Obuf  = (u16*)(wsb + 111149056);           // [2048][3584] bf16 swz : 14,680,064 B
  float* biasc = (float*)(wsb + 125829120);       // [4608] f32

  // 1. cast hidden to bf16 (pre-swizzled GEMM-A panel)
  cvt_swz_kernel<<<(SLEN * DM / 8) / 256, 256, 0, stream>>>(hidden, hid_b);
  // 2. transpose+cast all weights into pre-swizzled B^T panels
  transpose_cvt_all_kernel<<<dim3(56, 112, 4), 256, 0, stream>>>(Wq, Wk, Wv, Wo, wqkvT, woT);
  pack_bias_kernel<<<18, 256, 0, stream>>>(bq, bk, bv, biasc);
  // 3. QKV projection (+bias), 256^2 8-phase, bf16 out
  gemm256_kernel<0><<<dim3(SLEN / 256, NQKVC / 256), 512, 0, stream>>>(
      hid_b, wqkvT, qkv, biasc, DM, DM, DM, NQKVC);
  // 4. RoPE + layout (Q pre-scaled, K pre-swizzled), V transpose (pre-swizzled)
  rope_layout_kernel<<<dim3(SLEN, 32), 128, 0, stream>>>(qkv, cosp, sinp, Qr, Kswz);
  v_transpose_kernel<<<dim3(64, 4, 4), dim3(32, 8), 0, stream>>>(qkv, Vswz);
  // 5. causal GQA flash attention (paired q-tiles for balance)
  attn_kernel<<<dim3(8, NHEAD), 256, 0, stream>>>(Qr, Kswz, Vswz, Obuf);
  // 6. output projection, 256^2 8-phase, f32 out
  gemm256_kernel<1><<<dim3(SLEN / 256, DM / 256), 512, 0, stream>>>(
      Obuf, woT, out, nullptr, DM, DM, DM, DM);
}

// Round 10
// 318.016 us; speedup vs baseline: 1.1325x; 1.1325x over previous
//
#include <hip/hip_runtime.h>
#include <math.h>

typedef unsigned short u16;
typedef __attribute__((ext_vector_type(4))) short short4v;
typedef __attribute__((ext_vector_type(8))) short short8;
typedef __attribute__((ext_vector_type(8))) __bf16 bf16x8;
typedef __attribute__((ext_vector_type(4))) float f32x4;
typedef __attribute__((ext_vector_type(16))) float f32x16;
typedef __attribute__((ext_vector_type(4))) int i32x4;

#define SLEN  2048
#define DM    3584
#define NQKVC 4608
#define HDIM  128
#define NHEAD 28
#define NKVH  4
#define GRP   7
// 1/sqrt(128) * log2(e): Q pre-scaled so attention works in base-2 exp
#define QSCALE 0.12751744f

#if __has_builtin(__builtin_amdgcn_exp2f)
#define EXP2(x) __builtin_amdgcn_exp2f(x)
#else
#define EXP2(x) exp2f(x)
#endif

__device__ __forceinline__ float b2f(u16 u){ union{unsigned i; float f;} v; v.i = ((unsigned)u)<<16; return v.f; }
__device__ __forceinline__ u16 f2b(float f){ union{float f; unsigned i;} v; v.f = f; unsigned r = v.i + 0x7FFFu + ((v.i>>16)&1u); return (u16)(r>>16); }

__device__ __forceinline__ f32x4 mfma16(short8 a, short8 b, f32x4 c){
  return __builtin_amdgcn_mfma_f32_16x16x32_bf16(__builtin_bit_cast(bf16x8,a), __builtin_bit_cast(bf16x8,b), c, 0, 0, 0);
}
__device__ __forceinline__ f32x16 mfma32(short8 a, short8 b, f32x16 c){
  return __builtin_amdgcn_mfma_f32_32x32x16_bf16(__builtin_bit_cast(bf16x8,a), __builtin_bit_cast(bf16x8,b), c, 0, 0, 0);
}
__device__ __forceinline__ f32x16 zero16(){
  f32x16 z;
  #pragma unroll
  for (int i = 0; i < 16; ++i) z[i] = 0.f;
  return z;
}

__device__ __forceinline__ void gload_lds16(const u16* g, u16* l){
  __builtin_amdgcn_global_load_lds((const __attribute__((address_space(1))) void*)g,
                                   (__attribute__((address_space(3))) void*)l, 16, 0, 0);
}

// ---------------- cast f32 -> bf16 with per-row swizzle (GEMM-A layout) ----------------
// element (r,k) stored at col (k & ~63) | ((k ^ ((r&7)<<3)) & 63)  [8-elem groups]
__global__ void cvt_swz_kernel(const float* __restrict__ src, u16* __restrict__ dst){
  int idx = blockIdx.x * blockDim.x + threadIdx.x;      // one 8-elem group each; grid exact
  int r = idx / (DM / 8), g = idx % (DM / 8);
  const float4* s4 = (const float4*)(src + (size_t)idx * 8);
  float4 a = s4[0], b = s4[1];
  short8 o;
  o[0]=(short)f2b(a.x); o[1]=(short)f2b(a.y); o[2]=(short)f2b(a.z); o[3]=(short)f2b(a.w);
  o[4]=(short)f2b(b.x); o[5]=(short)f2b(b.y); o[6]=(short)f2b(b.z); o[7]=(short)f2b(b.w);
  int gs = (g & ~7) | ((g & 7) ^ (r & 7));
  *(short8*)(dst + (size_t)r * DM + gs * 8) = o;
}

// ---------------- merged transpose+cast for Wq/Wk/Wv/Wo (swizzled B^T panels) ----------
__global__ void transpose_cvt_all_kernel(const float* __restrict__ Wq, const float* __restrict__ Wk,
                                         const float* __restrict__ Wv, const float* __restrict__ Wo,
                                         u16* __restrict__ wqkvT, u16* __restrict__ woT){
  int z = blockIdx.z;
  const float* src; u16* dst; int N;
  if (z == 0){ src = Wq; dst = wqkvT;                          N = DM;  }
  else if (z == 1){ src = Wk; dst = wqkvT + (size_t)DM * DM;   N = 512; }
  else if (z == 2){ src = Wv; dst = wqkvT + (size_t)(DM+512)*DM; N = 512; }
  else { src = Wo; dst = woT; N = DM; }
  int nb = blockIdx.y * 32;
  if (nb >= N) return;
  int kb = blockIdx.x * 64;

  __shared__ u16 lt[32 * 68];
  int t = threadIdx.x, tx = t & 7, ty = t >> 3;   // ty 0..31
  #pragma unroll
  for (int i = 0; i < 2; ++i){
    int k = ty + 32 * i;
    float4 v = *(const float4*)(src + (size_t)(kb + k) * N + nb + tx * 4);
    lt[(tx * 4 + 0) * 68 + k] = f2b(v.x);
    lt[(tx * 4 + 1) * 68 + k] = f2b(v.y);
    lt[(tx * 4 + 2) * 68 + k] = f2b(v.z);
    lt[(tx * 4 + 3) * 68 + k] = f2b(v.w);
  }
  __syncthreads();
  int n = ty, kc = tx;
  short4v lo = *(const short4v*)(lt + n * 68 + kc * 8);
  short4v hi4 = *(const short4v*)(lt + n * 68 + kc * 8 + 4);
  short8 o;
  o[0]=lo[0]; o[1]=lo[1]; o[2]=lo[2]; o[3]=lo[3];
  o[4]=hi4[0]; o[5]=hi4[1]; o[6]=hi4[2]; o[7]=hi4[3];
  int kcs = kc ^ (ty & 7);                          // row-keyed swizzle within 64-col chunk
  *(short8*)(dst + (size_t)(nb + n) * DM + kb + kcs * 8) = o;
}

// ---------------- bias pack: [bq | bk | bv] -> f32[4608] ----------------
__global__ void pack_bias_kernel(const float* bq, const float* bk, const float* bv, float* o){
  int n = blockIdx.x * 256 + threadIdx.x;
  if (n >= NQKVC) return;
  o[n] = (n < DM) ? bq[n] : (n < DM + 512 ? bk[n - DM] : bv[n - DM - 512]);
}

// ---------------- 128x128 2-phase double-buffered bf16 GEMM (BK=64) ----------------
// C[M][N] = A[M][K] * B^T[N][K] (+bias). A,B PRE-SWIZZLED in global (col ^= (row&7)<<3
// within 64-col chunks) so linear global_load_lds lands a conflict-free LDS image.
// 256 threads = 4 waves (2x2), per-wave 64x64 out. LDS 64 KB (2 bufs) -> 2 blocks/CU.
// T3-minimal pipeline: stage(next) || ds_read+MFMA(cur); one __syncthreads per K-step.
template<int OUTF32>
__global__ __launch_bounds__(256, 2)
void gemm_bt_kernel(const u16* __restrict__ A, const u16* __restrict__ B, void* __restrict__ Cout,
                    const float* __restrict__ bias, int K, int lda, int ldb, int ldc){
  __shared__ __align__(16) u16 As[2][8192];
  __shared__ __align__(16) u16 Bs[2][8192];
  int t = threadIdx.x, w = t >> 6, l = t & 63, lm = l & 15, lh = l >> 4;
  int m0 = blockIdx.x * 128, n0 = blockIdx.y * 128;
  int wm = w >> 1, wn = w & 1;
  int swz = (lm & 7) << 3;
  int nkt = K >> 6;

  f32x4 acc[4][4];
  #pragma unroll
  for (int i = 0; i < 4; ++i)
    #pragma unroll
    for (int j = 0; j < 4; ++j) acc[i][j] = (f32x4){0.f, 0.f, 0.f, 0.f};

  const u16* ag = A + (size_t)(m0 + (t >> 3)) * lda + (t & 7) * 8;
  const u16* bg = B + (size_t)(n0 + (t >> 3)) * ldb + (t & 7) * 8;

#define STG(kt, buf) do{ int _ko = (kt) << 6; \
    _Pragma("unroll") for (int i = 0; i < 4; ++i){ \
      gload_lds16(ag + (size_t)(i * 32) * lda + _ko, &As[buf][i * 2048 + t * 8]); \
      gload_lds16(bg + (size_t)(i * 32) * ldb + _ko, &Bs[buf][i * 2048 + t * 8]); \
    } }while(0)
#define RDFRAGS(buf) do{ \
    _Pragma("unroll") for (int mi = 0; mi < 4; ++mi) \
      _Pragma("unroll") for (int ks = 0; ks < 2; ++ks) \
        af[mi][ks] = *(const short8*)(&As[buf][(wm*64 + mi*16 + lm)*64 + ((ks*32 + lh*8) ^ swz)]); \
    _Pragma("unroll") for (int ni = 0; ni < 4; ++ni) \
      _Pragma("unroll") for (int ks = 0; ks < 2; ++ks) \
        bf[ni][ks] = *(const short8*)(&Bs[buf][(wn*64 + ni*16 + lm)*64 + ((ks*32 + lh*8) ^ swz)]); }while(0)
#define MFMAS do{ \
    _Pragma("unroll") for (int ks = 0; ks < 2; ++ks) \
      _Pragma("unroll") for (int mi = 0; mi < 4; ++mi) \
        _Pragma("unroll") for (int ni = 0; ni < 4; ++ni) \
          acc[mi][ni] = mfma16(af[mi][ks], bf[ni][ks], acc[mi][ni]); }while(0)

  // prologue: stage tile 0
  STG(0, 0);
  __syncthreads();

  short8 af[4][2], bf[4][2];
  int buf = 0;
  for (int kt = 0; kt < nkt - 1; ++kt){
    STG(kt + 1, buf ^ 1);                                   // overlap: next tile in flight
    RDFRAGS(buf);
    asm volatile("s_waitcnt lgkmcnt(0)" ::: "memory");      // ds_reads done
    __builtin_amdgcn_sched_barrier(0);                      // rule #18: pin MFMA after wait
    __builtin_amdgcn_s_setprio(1);
    MFMAS;
    __builtin_amdgcn_s_setprio(0);
    __syncthreads();                                        // drains vmcnt(0): next buf ready
    buf ^= 1;
  }
  // last tile (no stage)
  RDFRAGS(buf);
  asm volatile("s_waitcnt lgkmcnt(0)" ::: "memory");
  __builtin_amdgcn_sched_barrier(0);
  MFMAS;

  // epilogue
  #pragma unroll
  for (int mi = 0; mi < 4; ++mi){
    #pragma unroll
    for (int ni = 0; ni < 4; ++ni){
      int n = n0 + wn * 64 + ni * 16 + lm;
      float bv = OUTF32 ? 0.f : bias[n];
      #pragma unroll
      for (int j = 0; j < 4; ++j){
        int m = m0 + wm * 64 + mi * 16 + lh * 4 + j;
        float v = acc[mi][ni][j] + bv;
        if (OUTF32) ((float*)Cout)[(size_t)m * ldc + n] = v;
        else        ((u16*)Cout)[(size_t)m * ldc + n]  = f2b(v);
      }
    }
  }
#undef STG
#undef RDFRAGS
#undef MFMAS
}

// ---------------- RoPE + head layout ----------------
// Qr[28][S][128] row-major (PRE-SCALED by QSCALE); Kswz[4][32][8192]: per 64x128 tile,
// u16 index r*128 + (d ^ ((r&7)<<3)) (XOR-swizzled LDS image for linear global_load_lds)
__global__ void rope_layout_kernel(const u16* __restrict__ qkv, const float* __restrict__ cosp,
                                   const float* __restrict__ sinp, u16* __restrict__ Qr, u16* __restrict__ Kswz){
  int s = blockIdx.x, y = blockIdx.y, d = threadIdx.x;
  int base = (y < NHEAD) ? y * HDIM : DM + (y - NHEAD) * HDIM;
  const u16* row = qkv + (size_t)s * NQKVC + base;
  float x  = b2f(row[d]);
  float xp = b2f(row[d < 64 ? d + 64 : d - 64]);
  float rot = (d < 64) ? -xp : xp;
  int axis = (d < 32) ? 0 : (d < 80 ? 1 : 2);
  float c  = cosp[axis * (SLEN * HDIM) + s * HDIM + d];
  float sn = sinp[axis * (SLEN * HDIM) + s * HDIM + d];
  float val = x * c + rot * sn;
  if (y < NHEAD){
    Qr[((size_t)y * SLEN + s) * HDIM + d] = f2b(val * QSCALE);
  } else {
    int kh = y - NHEAD, kt = s >> 6, rr = s & 63;
    Kswz[(((size_t)kh * 32 + kt) << 13) + rr * 128 + (d ^ ((rr & 7) << 3))] = f2b(val);
  }
}

// ---------------- V transpose into swizzled tiles ----------------
// Vswz[4][32][8192]: per 128x64 tile (row=d, col=s%64), u16 index d*64 + (c ^ ((d&7)<<3))
__global__ void v_transpose_kernel(const u16* __restrict__ qkv, u16* __restrict__ Vswz){
  __shared__ u16 tile[32][34];
  int kh = blockIdx.z;
  int sb = blockIdx.x * 32, db = blockIdx.y * 32;
  int tx = threadIdx.x, ty = threadIdx.y;
  #pragma unroll
  for (int i = 0; i < 4; ++i){
    int s = sb + ty + i * 8;
    tile[ty + i * 8][tx] = qkv[(size_t)s * NQKVC + DM + 512 + kh * HDIM + db + tx];
  }
  __syncthreads();
  #pragma unroll
  for (int i = 0; i < 4; ++i){
    int d = db + ty + i * 8;
    int s = sb + tx;
    Vswz[(((size_t)kh * 32 + (s >> 6)) << 13) + d * 64 + ((s & 63) ^ ((d & 7) << 3))] = tile[tx][ty + i * 8];
  }
}

// ---------------- causal GQA flash attention (swapped QK^T, 32x32 MFMA) ----------------
#define PV_HALF(PK, KH2) do { \
  unsigned s0 = __shfl_xor(hi ? PK[0] : PK[2], 32, 64); \
  unsigned s1 = __shfl_xor(hi ? PK[1] : PK[3], 32, 64); \
  unsigned s2 = __shfl_xor(hi ? PK[4] : PK[6], 32, 64); \
  unsigned s3 = __shfl_xor(hi ? PK[5] : PK[7], 32, 64); \
  i32x4 fa = { (int)(hi ? s0 : PK[0]), (int)(hi ? s1 : PK[1]), \
               (int)(hi ? PK[2] : s0), (int)(hi ? PK[3] : s1) }; \
  i32x4 fb = { (int)(hi ? s2 : PK[4]), (int)(hi ? s3 : PK[5]), \
               (int)(hi ? PK[6] : s2), (int)(hi ? PK[7] : s3) }; \
  short8 pf0 = __builtin_bit_cast(short8, fa); \
  short8 pf1 = __builtin_bit_cast(short8, fb); \
  _Pragma("unroll") \
  for (int dt = 0; dt < 4; ++dt){ \
    const u16* vrow = vsb + (dt * 32 + lq) * 64; \
    short8 vf0 = *(const short8*)(vrow + (((KH2) * 32 + hi * 8) ^ swz)); \
    short8 vf1 = *(const short8*)(vrow + (((KH2) * 32 + 16 + hi * 8) ^ swz)); \
    oacc[dt] = mfma32(vf0, pf0, oacc[dt]); \
    oacc[dt] = mfma32(vf1, pf1, oacc[dt]); \
  } \
} while(0)

__global__ __launch_bounds__(256, 1)
void attn_kernel(const u16* __restrict__ Qr, const u16* __restrict__ Kswz,
                 const u16* __restrict__ Vswz, u16* __restrict__ O){
  int pairid = blockIdx.x, h = blockIdx.y, kh = h / GRP;
  int t = threadIdx.x, w = t >> 6, l = t & 63;
  int lq = l & 31, hi = l >> 5;
  int swz = (l & 7) << 3;

  __shared__ __align__(16) u16 smem[32768];  // Ks dbuf @0, Vs dbuf @16384; epilogue scratch reuses

  const u16* kg = Kswz + (((size_t)kh * 32) << 13) + t * 8;
  const u16* vg = Vswz + (((size_t)kh * 32) << 13) + t * 8;

  for (int half = 0; half < 2; ++half){
    int qt = half ? (15 - pairid) : pairid;
    int q0 = qt * 128;
    int qrow = q0 + w * 32 + lq;
    int ktstage = 2 * qt + 1;
    int ktw = 2 * qt + (w >> 1);

    __syncthreads();   // protect LDS reuse across passes

    short8 qf[8];
    const u16* qb = Qr + ((size_t)h * SLEN + qrow) * HDIM + hi * 8;
    #pragma unroll
    for (int dc = 0; dc < 8; ++dc) qf[dc] = *(const short8*)(qb + dc * 16);

    f32x16 oacc[4];
    #pragma unroll
    for (int i = 0; i < 4; ++i) oacc[i] = zero16();
    float mrun = -1.0e30f, lsum = 0.f;

    #pragma unroll
    for (int i = 0; i < 4; ++i){
      gload_lds16(kg + i * 2048, smem + t * 8 + i * 2048);
      gload_lds16(vg + i * 2048, smem + 16384 + t * 8 + i * 2048);
    }
    asm volatile("s_waitcnt vmcnt(0)" ::: "memory");
    __syncthreads();

    int buf = 0;
    for (int kt = 0; kt <= ktstage; ++kt){
      if (kt < ktstage){
        const u16* kg2 = kg + ((size_t)(kt + 1) << 13);
        const u16* vg2 = vg + ((size_t)(kt + 1) << 13);
        u16* kdst = smem + ((buf ^ 1) << 13) + t * 8;
        u16* vdst = smem + 16384 + ((buf ^ 1) << 13) + t * 8;
        #pragma unroll
        for (int i = 0; i < 4; ++i){
          gload_lds16(kg2 + i * 2048, kdst + i * 2048);
          gload_lds16(vg2 + i * 2048, vdst + i * 2048);
        }
      }
      if (kt <= ktw){
        const u16* ksb = smem + (buf << 13);
        const u16* vsb = smem + 16384 + (buf << 13);
        f32x16 st0 = zero16(), st1 = zero16();
        #pragma unroll
        for (int dc = 0; dc < 8; ++dc){
          int dofs = (dc * 16 + hi * 8) ^ swz;
          short8 kf0 = *(const short8*)(ksb + lq * 128 + dofs);
          short8 kf1 = *(const short8*)(ksb + (32 + lq) * 128 + dofs);
          st0 = mfma32(kf0, qf[dc], st0);
          st1 = mfma32(kf1, qf[dc], st1);
        }
        if (kt == ktw){
          int kbase = kt * 64 - qrow;
          #pragma unroll
          for (int i = 0; i < 16; ++i){
            int k0 = (i & 3) + 8 * (i >> 2) + 4 * hi;
            if (kbase + k0 > 0)      st0[i] = -3.0e38f;
            if (kbase + 32 + k0 > 0) st1[i] = -3.0e38f;
          }
        }
        float pmax = st0[0];
        #pragma unroll
        for (int i = 1; i < 16; ++i) pmax = fmaxf(pmax, st0[i]);
        #pragma unroll
        for (int i = 0; i < 16; ++i) pmax = fmaxf(pmax, st1[i]);
        if (!__all(pmax - mrun <= 8.f)){
          float mo = fmaxf(pmax, __shfl_xor(pmax, 32, 64));
          float mn = fmaxf(mrun, mo);
          float al = EXP2(mrun - mn);
          mrun = mn;
          lsum *= al;
          #pragma unroll
          for (int i2 = 0; i2 < 4; ++i2)
            #pragma unroll
            for (int i = 0; i < 16; ++i) oacc[i2][i] *= al;
        }
        unsigned pk0[8], pk1[8];
        float ls = 0.f;
        #pragma unroll
        for (int m = 0; m < 8; ++m){
          float a0 = EXP2(st0[2*m] - mrun), b0 = EXP2(st0[2*m+1] - mrun);
          float a1 = EXP2(st1[2*m] - mrun), b1 = EXP2(st1[2*m+1] - mrun);
          ls += (a0 + b0) + (a1 + b1);
          pk0[m] = (unsigned)f2b(a0) | ((unsigned)f2b(b0) << 16);
          pk1[m] = (unsigned)f2b(a1) | ((unsigned)f2b(b1) << 16);
        }
        lsum += ls;
        PV_HALF(pk0, 0);
        PV_HALF(pk1, 1);
      }
      asm volatile("s_waitcnt vmcnt(0)" ::: "memory");
      __syncthreads();
      buf ^= 1;
    }

    float lt = lsum + __shfl_xor(lsum, 32, 64);
    float inv = 1.0f / lt;
    u16* scr = smem + w * 4352;
    #pragma unroll
    for (int dt = 0; dt < 4; ++dt){
      #pragma unroll
      for (int m = 0; m < 8; ++m){
        float a = oacc[dt][2*m] * inv, b = oacc[dt][2*m+1] * inv;
        unsigned pw = (unsigned)f2b(a) | ((unsigned)f2b(b) << 16);
        int d = dt * 32 + 8 * (m >> 1) + 2 * (m & 1) + 4 * hi;
        *(unsigned*)(scr + lq * 136 + d) = pw;
      }
    }
    int r2 = l >> 1, cbase = (l & 1) * 8;
    int srow = q0 + w * 32 + r2;
    u16* orow = O + (size_t)srow * DM + h * HDIM;
    // store with per-row swizzle so Obuf is a valid pre-swizzled GEMM-A panel
    #pragma unroll
    for (int c = 0; c < 8; ++c){
      int gi = (l & 1) + 2 * c;
      int gs = (gi & 8) | ((gi & 7) ^ (srow & 7));
      short8 v8 = *(const short8*)(scr + r2 * 136 + cbase + c * 16);
      *(short8*)(orow + gs * 8) = v8;
    }
  }
}

extern "C" void kernel_launch(void* const* d_in, const int* in_sizes, int n_in,
                              void* d_out, int out_size, void* d_ws, size_t ws_size,
                              hipStream_t stream){
  const float* hidden = (const float*)d_in[0];
  // d_in[1] = attention_mask (causal additive, exploited analytically)
  const float* cosp = (const float*)d_in[2];
  const float* sinp = (const float*)d_in[3];
  const float* Wq = (const float*)d_in[4];
  const float* bq = (const float*)d_in[5];
  const float* Wk = (const float*)d_in[6];
  const float* bk = (const float*)d_in[7];
  const float* Wv = (const float*)d_in[8];
  const float* bv = (const float*)d_in[9];
  const float* Wo = (const float*)d_in[10];
  float* out = (float*)d_out;

  char* wsb = (char*)d_ws;
  u16* hid_b = (u16*)(wsb);                       // [2048][3584] bf16 swz : 14,680,064 B
  u16* wqkvT = (u16*)(wsb + 14680064);            // [4608][3584] bf16 swz : 33,030,144 B
  u16* woT   = (u16*)(wsb + 47710208);            // [3584][3584] bf16 swz : 25,690,112 B
  u16* qkv   = (u16*)(wsb + 73400320);            // [2048][4608] bf16     : 18,874,368 B
  u16* Qr    = (u16*)(wsb + 92274688);            // [28][2048][128]       : 14,680,064 B
  u16* Kswz  = (u16*)(wsb + 106954752);           // [4][32][8192]         :  2,097,152 B
  u16* Vswz  = (u16*)(wsb + 109051904);           // [4][32][8192]         :  2,097,152 B
  u16* Obuf  = (u16*)(wsb + 111149056);           // [2048][3584] bf16 swz : 14,680,064 B
  float* biasc = (float*)(wsb + 125829120);       // [4608] f32

  // 1. cast hidden to bf16 (pre-swizzled GEMM-A panel)
  cvt_swz_kernel<<<(SLEN * DM / 8) / 256, 256, 0, stream>>>(hidden, hid_b);
  // 2. transpose+cast all weights into pre-swizzled B^T panels
  transpose_cvt_all_kernel<<<dim3(56, 112, 4), 256, 0, stream>>>(Wq, Wk, Wv, Wo, wqkvT, woT);
  pack_bias_kernel<<<18, 256, 0, stream>>>(bq, bk, bv, biasc);
  // 3. QKV projection (+bias), 128^2 dbuf 2-phase, bf16 out
  gemm_bt_kernel<0><<<dim3(SLEN / 128, NQKVC / 128), 256, 0, stream>>>(
      hid_b, wqkvT, qkv, biasc, DM, DM, DM, NQKVC);
  // 4. RoPE + layout (Q pre-scaled, K pre-swizzled), V transpose (pre-swizzled)
  rope_layout_kernel<<<dim3(SLEN, 32), 128, 0, stream>>>(qkv, cosp, sinp, Qr, Kswz);
  v_transpose_kernel<<<dim3(64, 4, 4), dim3(32, 8), 0, stream>>>(qkv, Vswz);
  // 5. causal GQA flash attention (paired q-tiles for balance)
  attn_kernel<<<dim3(8, NHEAD), 256, 0, stream>>>(Qr, Kswz, Vswz, Obuf);
  // 6. output projection, 128^2 dbuf 2-phase, f32 out
  gemm_bt_kernel<1><<<dim3(SLEN / 128, DM / 128), 256, 0, stream>>>(
      Obuf, woT, out, nullptr, DM, DM, DM, DM);
}

// Round 11
// 299.946 us; speedup vs baseline: 1.2007x; 1.0602x over previous
//
#include <hip/hip_runtime.h>
#include <math.h>

typedef unsigned short u16;
typedef __attribute__((ext_vector_type(4))) short short4v;
typedef __attribute__((ext_vector_type(8))) short short8;
typedef __attribute__((ext_vector_type(8))) __bf16 bf16x8;
typedef __attribute__((ext_vector_type(4))) float f32x4;
typedef __attribute__((ext_vector_type(16))) float f32x16;
typedef __attribute__((ext_vector_type(4))) int i32x4;

#define SLEN  2048
#define DM    3584
#define NQKVC 4608
#define HDIM  128
#define NHEAD 28
#define NKVH  4
#define GRP   7
// 1/sqrt(128) * log2(e): Q pre-scaled so attention works in base-2 exp
#define QSCALE 0.12751744f

#if __has_builtin(__builtin_amdgcn_exp2f)
#define EXP2(x) __builtin_amdgcn_exp2f(x)
#else
#define EXP2(x) exp2f(x)
#endif

__device__ __forceinline__ float b2f(u16 u){ union{unsigned i; float f;} v; v.i = ((unsigned)u)<<16; return v.f; }
__device__ __forceinline__ u16 f2b(float f){ union{float f; unsigned i;} v; v.f = f; unsigned r = v.i + 0x7FFFu + ((v.i>>16)&1u); return (u16)(r>>16); }

__device__ __forceinline__ f32x4 mfma16(short8 a, short8 b, f32x4 c){
  return __builtin_amdgcn_mfma_f32_16x16x32_bf16(__builtin_bit_cast(bf16x8,a), __builtin_bit_cast(bf16x8,b), c, 0, 0, 0);
}
__device__ __forceinline__ f32x16 mfma32(short8 a, short8 b, f32x16 c){
  return __builtin_amdgcn_mfma_f32_32x32x16_bf16(__builtin_bit_cast(bf16x8,a), __builtin_bit_cast(bf16x8,b), c, 0, 0, 0);
}
__device__ __forceinline__ f32x16 zero16(){
  f32x16 z;
  #pragma unroll
  for (int i = 0; i < 16; ++i) z[i] = 0.f;
  return z;
}

__device__ __forceinline__ void gload_lds16(const u16* g, u16* l){
  __builtin_amdgcn_global_load_lds((const __attribute__((address_space(1))) void*)g,
                                   (__attribute__((address_space(3))) void*)l, 16, 0, 0);
}

// ======== GEMM operand swizzle (BK=32 compatible) ========
// Within each 32-col chunk, 8-elem group g of row r is stored at g ^ ((r>>1)&3).
// Fragment read (16 rows x 16B) then touches 8 distinct bank-quads (2-way = free).

// ---------------- cast f32 -> bf16 with per-row swizzle (GEMM-A panel) ----------------
__global__ void cvt_swz_kernel(const float* __restrict__ src, u16* __restrict__ dst){
  int idx = blockIdx.x * blockDim.x + threadIdx.x;      // one 8-elem group each; grid exact
  int r = idx / (DM / 8), g = idx % (DM / 8);
  const float4* s4 = (const float4*)(src + (size_t)idx * 8);
  float4 a = s4[0], b = s4[1];
  short8 o;
  o[0]=(short)f2b(a.x); o[1]=(short)f2b(a.y); o[2]=(short)f2b(a.z); o[3]=(short)f2b(a.w);
  o[4]=(short)f2b(b.x); o[5]=(short)f2b(b.y); o[6]=(short)f2b(b.z); o[7]=(short)f2b(b.w);
  int gs = (g & ~3) | ((g & 3) ^ ((r >> 1) & 3));
  *(short8*)(dst + (size_t)r * DM + gs * 8) = o;
}

// ---------------- merged transpose+cast for Wq/Wk/Wv/Wo (swizzled B^T panels) ----------
__global__ void transpose_cvt_all_kernel(const float* __restrict__ Wq, const float* __restrict__ Wk,
                                         const float* __restrict__ Wv, const float* __restrict__ Wo,
                                         u16* __restrict__ wqkvT, u16* __restrict__ woT){
  int z = blockIdx.z;
  const float* src; u16* dst; int N;
  if (z == 0){ src = Wq; dst = wqkvT;                          N = DM;  }
  else if (z == 1){ src = Wk; dst = wqkvT + (size_t)DM * DM;   N = 512; }
  else if (z == 2){ src = Wv; dst = wqkvT + (size_t)(DM+512)*DM; N = 512; }
  else { src = Wo; dst = woT; N = DM; }
  int nb = blockIdx.y * 32;
  if (nb >= N) return;
  int kb = blockIdx.x * 64;

  __shared__ u16 lt[32 * 68];
  int t = threadIdx.x, tx = t & 7, ty = t >> 3;   // ty 0..31
  #pragma unroll
  for (int i = 0; i < 2; ++i){
    int k = ty + 32 * i;
    float4 v = *(const float4*)(src + (size_t)(kb + k) * N + nb + tx * 4);
    lt[(tx * 4 + 0) * 68 + k] = f2b(v.x);
    lt[(tx * 4 + 1) * 68 + k] = f2b(v.y);
    lt[(tx * 4 + 2) * 68 + k] = f2b(v.z);
    lt[(tx * 4 + 3) * 68 + k] = f2b(v.w);
  }
  __syncthreads();
  int n = ty, kc = tx;
  short4v lo = *(const short4v*)(lt + n * 68 + kc * 8);
  short4v hi4 = *(const short4v*)(lt + n * 68 + kc * 8 + 4);
  short8 o;
  o[0]=lo[0]; o[1]=lo[1]; o[2]=lo[2]; o[3]=lo[3];
  o[4]=hi4[0]; o[5]=hi4[1]; o[6]=hi4[2]; o[7]=hi4[3];
  int kcs = (kc & 4) | ((kc & 3) ^ ((ty >> 1) & 3));   // row-keyed swizzle in 32-col chunks
  *(short8*)(dst + (size_t)(nb + n) * DM + kb + kcs * 8) = o;
}

// ---------------- bias pack: [bq | bk | bv] -> f32[4608] ----------------
__global__ void pack_bias_kernel(const float* bq, const float* bk, const float* bv, float* o){
  int n = blockIdx.x * 256 + threadIdx.x;
  if (n >= NQKVC) return;
  o[n] = (n < DM) ? bq[n] : (n < DM + 512 ? bk[n - DM] : bv[n - DM - 512]);
}

// ---------------- 128x128 depth-3 counted-vmcnt bf16 GEMM (BK=32) ----------------
// C[M][N] = A[M][K] * B^T[N][K] (+bias). A,B PRE-SWIZZLED per the 32-chunk rule.
// 256 threads = 4 waves (2x2), per-wave 64x64. LDS = 3 bufs x (8KB A + 8KB B) = 48KB
// -> 3 blocks/CU. Pipeline: step kt stages tile kt+2; end-of-step waits vmcnt(4)
// (tile kt+1 landed; kt+2 stays in flight ACROSS the barrier - T4). Raw s_barrier,
// never vmcnt(0) in the loop. Ghost re-stages keep the ledger uniform at the tail.
// XCD-bijective block remap: each XCD owns a contiguous N-chunk (B slice ~4MB -> L2).
template<int OUTF32>
__global__ __launch_bounds__(256, 4)
void gemm_bt_kernel(const u16* __restrict__ A, const u16* __restrict__ B, void* __restrict__ Cout,
                    const float* __restrict__ bias, int K, int lda, int ldb, int ldc){
  __shared__ __align__(16) u16 As[3][4096];
  __shared__ __align__(16) u16 Bs[3][4096];
  int t = threadIdx.x, w = t >> 6, l = t & 63, lm = l & 15, lh = l >> 4;
  int nwgx = gridDim.x;
  int lin = blockIdx.x + nwgx * blockIdx.y;
  int cpx = (nwgx * gridDim.y) >> 3;               // grids are %8==0 (576/448)
  int wk = (lin & 7) * cpx + (lin >> 3);
  int m0 = (wk % nwgx) * 128, n0 = (wk / nwgx) * 128;
  int wm = w >> 1, wn = w & 1;
  int nkt = K >> 5;
  int kgrp = (lh ^ ((lm >> 1) & 3)) * 8;           // swizzled k-group byte... elem offset

  f32x4 acc[4][4];
  #pragma unroll
  for (int i = 0; i < 4; ++i)
    #pragma unroll
    for (int j = 0; j < 4; ++j) acc[i][j] = (f32x4){0.f, 0.f, 0.f, 0.f};

  // staging: thread t -> rows (t>>2, t>>2+64), group t&3 (8 elems)
  const u16* ag = A + (size_t)(m0 + (t >> 2)) * lda + (t & 3) * 8;
  const u16* bg = B + (size_t)(n0 + (t >> 2)) * ldb + (t & 3) * 8;
  u16* asl = &As[0][(t >> 2) * 32 + (t & 3) * 8];
  u16* bsl = &Bs[0][(t >> 2) * 32 + (t & 3) * 8];

#define STG(kt, buf) do{ int _kt = ((kt) < nkt) ? (kt) : ((kt) - 3); int _ko = _kt << 5; \
    gload_lds16(ag + _ko,            asl + (buf) * 4096); \
    gload_lds16(ag + 64 * lda + _ko, asl + (buf) * 4096 + 2048); \
    gload_lds16(bg + _ko,            bsl + (buf) * 4096); \
    gload_lds16(bg + 64 * ldb + _ko, bsl + (buf) * 4096 + 2048); }while(0)
#define RDFRAGS(buf) do{ \
    _Pragma("unroll") for (int mi = 0; mi < 4; ++mi) \
      af[mi] = *(const short8*)(&As[buf][(wm*64 + mi*16 + lm)*32 + kgrp]); \
    _Pragma("unroll") for (int ni = 0; ni < 4; ++ni) \
      bf[ni] = *(const short8*)(&Bs[buf][(wn*64 + ni*16 + lm)*32 + kgrp]); }while(0)
#define MFMAS do{ \
    _Pragma("unroll") for (int mi = 0; mi < 4; ++mi) \
      _Pragma("unroll") for (int ni = 0; ni < 4; ++ni) \
        acc[mi][ni] = mfma16(af[mi], bf[ni], acc[mi][ni]); }while(0)

  // prologue: tiles 0 and 1 in flight; wait tile 0 (vmcnt 8->4)
  STG(0, 0);
  STG(1, 1);
  asm volatile("s_waitcnt vmcnt(4)" ::: "memory");
  __builtin_amdgcn_sched_barrier(0);
  __builtin_amdgcn_s_barrier();

  short8 af[4], bf[4];
  int cur = 0;
  for (int kt = 0; kt < nkt; ++kt){
    int nb = cur + 2; if (nb >= 3) nb -= 3;
    STG(kt + 2, nb);                                   // 2 steps ahead: ~600cy window
    RDFRAGS(cur);
    asm volatile("s_waitcnt lgkmcnt(0)" ::: "memory");
    __builtin_amdgcn_sched_barrier(0);                 // rule #18
    __builtin_amdgcn_s_setprio(1);
    MFMAS;
    __builtin_amdgcn_s_setprio(0);
    asm volatile("s_waitcnt vmcnt(4)" ::: "memory");   // tile kt+1 landed; kt+2 in flight
    __builtin_amdgcn_sched_barrier(0);
    __builtin_amdgcn_s_barrier();
    ++cur; if (cur == 3) cur = 0;
  }

  // epilogue
  #pragma unroll
  for (int mi = 0; mi < 4; ++mi){
    #pragma unroll
    for (int ni = 0; ni < 4; ++ni){
      int n = n0 + wn * 64 + ni * 16 + lm;
      float bv = OUTF32 ? 0.f : bias[n];
      #pragma unroll
      for (int j = 0; j < 4; ++j){
        int m = m0 + wm * 64 + mi * 16 + lh * 4 + j;
        float v = acc[mi][ni][j] + bv;
        if (OUTF32) ((float*)Cout)[(size_t)m * ldc + n] = v;
        else        ((u16*)Cout)[(size_t)m * ldc + n]  = f2b(v);
      }
    }
  }
#undef STG
#undef RDFRAGS
#undef MFMAS
}

// ---------------- RoPE + head layout ----------------
// Qr[28][S][128] row-major (PRE-SCALED by QSCALE); Kswz[4][32][8192]: per 64x128 tile,
// u16 index r*128 + (d ^ ((r&7)<<3)) (XOR-swizzled LDS image for linear global_load_lds)
__global__ void rope_layout_kernel(const u16* __restrict__ qkv, const float* __restrict__ cosp,
                                   const float* __restrict__ sinp, u16* __restrict__ Qr, u16* __restrict__ Kswz){
  int s = blockIdx.x, y = blockIdx.y, d = threadIdx.x;
  int base = (y < NHEAD) ? y * HDIM : DM + (y - NHEAD) * HDIM;
  const u16* row = qkv + (size_t)s * NQKVC + base;
  float x  = b2f(row[d]);
  float xp = b2f(row[d < 64 ? d + 64 : d - 64]);
  float rot = (d < 64) ? -xp : xp;
  int axis = (d < 32) ? 0 : (d < 80 ? 1 : 2);
  float c  = cosp[axis * (SLEN * HDIM) + s * HDIM + d];
  float sn = sinp[axis * (SLEN * HDIM) + s * HDIM + d];
  float val = x * c + rot * sn;
  if (y < NHEAD){
    Qr[((size_t)y * SLEN + s) * HDIM + d] = f2b(val * QSCALE);
  } else {
    int kh = y - NHEAD, kt = s >> 6, rr = s & 63;
    Kswz[(((size_t)kh * 32 + kt) << 13) + rr * 128 + (d ^ ((rr & 7) << 3))] = f2b(val);
  }
}

// ---------------- V transpose into swizzled tiles ----------------
// Vswz[4][32][8192]: per 128x64 tile (row=d, col=s%64), u16 index d*64 + (c ^ ((d&7)<<3))
__global__ void v_transpose_kernel(const u16* __restrict__ qkv, u16* __restrict__ Vswz){
  __shared__ u16 tile[32][34];
  int kh = blockIdx.z;
  int sb = blockIdx.x * 32, db = blockIdx.y * 32;
  int tx = threadIdx.x, ty = threadIdx.y;
  #pragma unroll
  for (int i = 0; i < 4; ++i){
    int s = sb + ty + i * 8;
    tile[ty + i * 8][tx] = qkv[(size_t)s * NQKVC + DM + 512 + kh * HDIM + db + tx];
  }
  __syncthreads();
  #pragma unroll
  for (int i = 0; i < 4; ++i){
    int d = db + ty + i * 8;
    int s = sb + tx;
    Vswz[(((size_t)kh * 32 + (s >> 6)) << 13) + d * 64 + ((s & 63) ^ ((d & 7) << 3))] = tile[tx][ty + i * 8];
  }
}

// ---------------- causal GQA flash attention (swapped QK^T, 32x32 MFMA) ----------------
#define PV_HALF(PK, KH2) do { \
  unsigned s0 = __shfl_xor(hi ? PK[0] : PK[2], 32, 64); \
  unsigned s1 = __shfl_xor(hi ? PK[1] : PK[3], 32, 64); \
  unsigned s2 = __shfl_xor(hi ? PK[4] : PK[6], 32, 64); \
  unsigned s3 = __shfl_xor(hi ? PK[5] : PK[7], 32, 64); \
  i32x4 fa = { (int)(hi ? s0 : PK[0]), (int)(hi ? s1 : PK[1]), \
               (int)(hi ? PK[2] : s0), (int)(hi ? PK[3] : s1) }; \
  i32x4 fb = { (int)(hi ? s2 : PK[4]), (int)(hi ? s3 : PK[5]), \
               (int)(hi ? PK[6] : s2), (int)(hi ? PK[7] : s3) }; \
  short8 pf0 = __builtin_bit_cast(short8, fa); \
  short8 pf1 = __builtin_bit_cast(short8, fb); \
  _Pragma("unroll") \
  for (int dt = 0; dt < 4; ++dt){ \
    const u16* vrow = vsb + (dt * 32 + lq) * 64; \
    short8 vf0 = *(const short8*)(vrow + (((KH2) * 32 + hi * 8) ^ swz)); \
    short8 vf1 = *(const short8*)(vrow + (((KH2) * 32 + 16 + hi * 8) ^ swz)); \
    oacc[dt] = mfma32(vf0, pf0, oacc[dt]); \
    oacc[dt] = mfma32(vf1, pf1, oacc[dt]); \
  } \
} while(0)

__global__ __launch_bounds__(256, 1)
void attn_kernel(const u16* __restrict__ Qr, const u16* __restrict__ Kswz,
                 const u16* __restrict__ Vswz, u16* __restrict__ O){
  int pairid = blockIdx.x, h = blockIdx.y, kh = h / GRP;
  int t = threadIdx.x, w = t >> 6, l = t & 63;
  int lq = l & 31, hi = l >> 5;
  int swz = (l & 7) << 3;

  __shared__ __align__(16) u16 smem[32768];  // Ks dbuf @0, Vs dbuf @16384; epilogue scratch reuses

  const u16* kg = Kswz + (((size_t)kh * 32) << 13) + t * 8;
  const u16* vg = Vswz + (((size_t)kh * 32) << 13) + t * 8;

  for (int half = 0; half < 2; ++half){
    int qt = half ? (15 - pairid) : pairid;
    int q0 = qt * 128;
    int qrow = q0 + w * 32 + lq;
    int ktstage = 2 * qt + 1;
    int ktw = 2 * qt + (w >> 1);

    __syncthreads();   // protect LDS reuse across passes

    short8 qf[8];
    const u16* qb = Qr + ((size_t)h * SLEN + qrow) * HDIM + hi * 8;
    #pragma unroll
    for (int dc = 0; dc < 8; ++dc) qf[dc] = *(const short8*)(qb + dc * 16);

    f32x16 oacc[4];
    #pragma unroll
    for (int i = 0; i < 4; ++i) oacc[i] = zero16();
    float mrun = -1.0e30f, lsum = 0.f;

    #pragma unroll
    for (int i = 0; i < 4; ++i){
      gload_lds16(kg + i * 2048, smem + t * 8 + i * 2048);
      gload_lds16(vg + i * 2048, smem + 16384 + t * 8 + i * 2048);
    }
    asm volatile("s_waitcnt vmcnt(0)" ::: "memory");
    __syncthreads();

    int buf = 0;
    for (int kt = 0; kt <= ktstage; ++kt){
      if (kt < ktstage){
        const u16* kg2 = kg + ((size_t)(kt + 1) << 13);
        const u16* vg2 = vg + ((size_t)(kt + 1) << 13);
        u16* kdst = smem + ((buf ^ 1) << 13) + t * 8;
        u16* vdst = smem + 16384 + ((buf ^ 1) << 13) + t * 8;
        #pragma unroll
        for (int i = 0; i < 4; ++i){
          gload_lds16(kg2 + i * 2048, kdst + i * 2048);
          gload_lds16(vg2 + i * 2048, vdst + i * 2048);
        }
      }
      if (kt <= ktw){
        const u16* ksb = smem + (buf << 13);
        const u16* vsb = smem + 16384 + (buf << 13);
        f32x16 st0 = zero16(), st1 = zero16();
        #pragma unroll
        for (int dc = 0; dc < 8; ++dc){
          int dofs = (dc * 16 + hi * 8) ^ swz;
          short8 kf0 = *(const short8*)(ksb + lq * 128 + dofs);
          short8 kf1 = *(const short8*)(ksb + (32 + lq) * 128 + dofs);
          st0 = mfma32(kf0, qf[dc], st0);
          st1 = mfma32(kf1, qf[dc], st1);
        }
        if (kt == ktw){
          int kbase = kt * 64 - qrow;
          #pragma unroll
          for (int i = 0; i < 16; ++i){
            int k0 = (i & 3) + 8 * (i >> 2) + 4 * hi;
            if (kbase + k0 > 0)      st0[i] = -3.0e38f;
            if (kbase + 32 + k0 > 0) st1[i] = -3.0e38f;
          }
        }
        float pmax = st0[0];
        #pragma unroll
        for (int i = 1; i < 16; ++i) pmax = fmaxf(pmax, st0[i]);
        #pragma unroll
        for (int i = 0; i < 16; ++i) pmax = fmaxf(pmax, st1[i]);
        if (!__all(pmax - mrun <= 8.f)){
          float mo = fmaxf(pmax, __shfl_xor(pmax, 32, 64));
          float mn = fmaxf(mrun, mo);
          float al = EXP2(mrun - mn);
          mrun = mn;
          lsum *= al;
          #pragma unroll
          for (int i2 = 0; i2 < 4; ++i2)
            #pragma unroll
            for (int i = 0; i < 16; ++i) oacc[i2][i] *= al;
        }
        unsigned pk0[8], pk1[8];
        float ls = 0.f;
        #pragma unroll
        for (int m = 0; m < 8; ++m){
          float a0 = EXP2(st0[2*m] - mrun), b0 = EXP2(st0[2*m+1] - mrun);
          float a1 = EXP2(st1[2*m] - mrun), b1 = EXP2(st1[2*m+1] - mrun);
          ls += (a0 + b0) + (a1 + b1);
          pk0[m] = (unsigned)f2b(a0) | ((unsigned)f2b(b0) << 16);
          pk1[m] = (unsigned)f2b(a1) | ((unsigned)f2b(b1) << 16);
        }
        lsum += ls;
        PV_HALF(pk0, 0);
        PV_HALF(pk1, 1);
      }
      asm volatile("s_waitcnt vmcnt(0)" ::: "memory");
      __syncthreads();
      buf ^= 1;
    }

    float lt = lsum + __shfl_xor(lsum, 32, 64);
    float inv = 1.0f / lt;
    u16* scr = smem + w * 4352;
    #pragma unroll
    for (int dt = 0; dt < 4; ++dt){
      #pragma unroll
      for (int m = 0; m < 8; ++m){
        float a = oacc[dt][2*m] * inv, b = oacc[dt][2*m+1] * inv;
        unsigned pw = (unsigned)f2b(a) | ((unsigned)f2b(b) << 16);
        int d = dt * 32 + 8 * (m >> 1) + 2 * (m & 1) + 4 * hi;
        *(unsigned*)(scr + lq * 136 + d) = pw;
      }
    }
    int r2 = l >> 1, cbase = (l & 1) * 8;
    int srow = q0 + w * 32 + r2;
    u16* orow = O + (size_t)srow * DM + h * HDIM;
    // store with per-row 32-chunk swizzle so Obuf is a valid pre-swizzled GEMM-A panel
    #pragma unroll
    for (int c = 0; c < 8; ++c){
      int gi = (l & 1) + 2 * c;
      int gs = (gi & 12) | ((gi & 3) ^ ((srow >> 1) & 3));
      short8 v8 = *(const short8*)(scr + r2 * 136 + cbase + c * 16);
      *(short8*)(orow + gs * 8) = v8;
    }
  }
}

extern "C" void kernel_launch(void* const* d_in, const int* in_sizes, int n_in,
                              void* d_out, int out_size, void* d_ws, size_t ws_size,
                              hipStream_t stream){
  const float* hidden = (const float*)d_in[0];
  // d_in[1] = attention_mask (causal additive, exploited analytically)
  const float* cosp = (const float*)d_in[2];
  const float* sinp = (const float*)d_in[3];
  const float* Wq = (const float*)d_in[4];
  const float* bq = (const float*)d_in[5];
  const float* Wk = (const float*)d_in[6];
  const float* bk = (const float*)d_in[7];
  const float* Wv = (const float*)d_in[8];
  const float* bv = (const float*)d_in[9];
  const float* Wo = (const float*)d_in[10];
  float* out = (float*)d_out;

  char* wsb = (char*)d_ws;
  u16* hid_b = (u16*)(wsb);                       // [2048][3584] bf16 swz : 14,680,064 B
  u16* wqkvT = (u16*)(wsb + 14680064);            // [4608][3584] bf16 swz : 33,030,144 B
  u16* woT   = (u16*)(wsb + 47710208);            // [3584][3584] bf16 swz : 25,690,112 B
  u16* qkv   = (u16*)(wsb + 73400320);            // [2048][4608] bf16     : 18,874,368 B
  u16* Qr    = (u16*)(wsb + 92274688);            // [28][2048][128]       : 14,680,064 B
  u16* Kswz  = (u16*)(wsb + 106954752);           // [4][32][8192]         :  2,097,152 B
  u16* Vswz  = (u16*)(wsb + 109051904);           // [4][32][8192]         :  2,097,152 B
  u16* Obuf  = (u16*)(wsb + 111149056);           // [2048][3584] bf16 swz : 14,680,064 B
  float* biasc = (float*)(wsb + 125829120);       // [4608] f32

  // 1. cast hidden to bf16 (pre-swizzled GEMM-A panel)
  cvt_swz_kernel<<<(SLEN * DM / 8) / 256, 256, 0, stream>>>(hidden, hid_b);
  // 2. transpose+cast all weights into pre-swizzled B^T panels
  transpose_cvt_all_kernel<<<dim3(56, 112, 4), 256, 0, stream>>>(Wq, Wk, Wv, Wo, wqkvT, woT);
  pack_bias_kernel<<<18, 256, 0, stream>>>(bq, bk, bv, biasc);
  // 3. QKV projection (+bias), depth-3 counted-vmcnt, bf16 out
  gemm_bt_kernel<0><<<dim3(SLEN / 128, NQKVC / 128), 256, 0, stream>>>(
      hid_b, wqkvT, qkv, biasc, DM, DM, DM, NQKVC);
  // 4. RoPE + layout (Q pre-scaled, K pre-swizzled), V transpose (pre-swizzled)
  rope_layout_kernel<<<dim3(SLEN, 32), 128, 0, stream>>>(qkv, cosp, sinp, Qr, Kswz);
  v_transpose_kernel<<<dim3(64, 4, 4), dim3(32, 8), 0, stream>>>(qkv, Vswz);
  // 5. causal GQA flash attention (paired q-tiles for balance)
  attn_kernel<<<dim3(8, NHEAD), 256, 0, stream>>>(Qr, Kswz, Vswz, Obuf);
  // 6. output projection, depth-3 counted-vmcnt, f32 out
  gemm_bt_kernel<1><<<dim3(SLEN / 128, DM / 128), 256, 0, stream>>>(
      Obuf, woT, out, nullptr, DM, DM, DM, DM);
}